// Round 4
// baseline (2102.211 us; speedup 1.0000x reference)
//
#include <hip/hip_runtime.h>

#define Hn 1024
#define Bn 8
#define Ln 4096
#define DIn 2048
#define NCH 64
#define CLn 64   // Ln / NCH

typedef __attribute__((ext_vector_type(8))) short short8;
typedef __attribute__((ext_vector_type(4))) short short4v;
typedef __attribute__((ext_vector_type(4))) float f32x4;

__device__ __forceinline__ float bf2f(short s) {
  return __uint_as_float(((unsigned)(unsigned short)s) << 16);
}
__device__ __forceinline__ short f2bf(float f) {
  unsigned u = __float_as_uint(f);
  u += 0x7fffu + ((u >> 16) & 1u);
  return (short)(u >> 16);
}
__device__ __forceinline__ float silu_f(float x) { return x / (1.f + __expf(-x)); }
__device__ __forceinline__ float softplus_f(float x) { return x > 20.f ? x : log1pf(__expf(x)); }

__device__ __forceinline__ void gld16(const short* g, short* l) {
  __builtin_amdgcn_global_load_lds((const __attribute__((address_space(1))) void*)g,
                                   (__attribute__((address_space(3))) void*)l, 16, 0, 0);
}

#define PFENCE() __builtin_amdgcn_sched_barrier(0)
#define PBAR()            \
  do {                    \
    PFENCE();             \
    __builtin_amdgcn_s_barrier(); \
    PFENCE();             \
  } while (0)

// ---------------- fp32 -> bf16 convert (x4 vectorized) ----------------
__global__ __launch_bounds__(256) void f2bf4_kernel(const float* __restrict__ in,
                                                    short* __restrict__ out, int n4) {
  int i = blockIdx.x * 256 + threadIdx.x;
  if (i < n4) {
    f32x4 v = ((const f32x4*)in)[i];
    short4v o;
    o.x = f2bf(v.x); o.y = f2bf(v.y); o.z = f2bf(v.z); o.w = f2bf(v.w);
    ((short4v*)out)[i] = o;
  }
}

// ---------------- adaLN modulation ----------------
__global__ __launch_bounds__(256) void modcalc_kernel(const float* __restrict__ c,
    const float* __restrict__ aw, const float* __restrict__ ab, float* __restrict__ mod) {
  int wid = blockIdx.x * 4 + (threadIdx.x >> 6);
  int lane = threadIdx.x & 63;
  int b = wid / 3072, n = wid - b * 3072;
  const f32x4* cr = (const f32x4*)(c + b * Hn);
  const f32x4* wr = (const f32x4*)(aw + (size_t)n * Hn);
  float s = 0.f;
#pragma unroll
  for (int i = 0; i < 4; ++i) {
    f32x4 cv = cr[lane + 64 * i];
    f32x4 wv = wr[lane + 64 * i];
    s += silu_f(cv.x) * wv.x + silu_f(cv.y) * wv.y + silu_f(cv.z) * wv.z + silu_f(cv.w) * wv.w;
  }
#pragma unroll
  for (int m = 1; m < 64; m <<= 1) s += __shfl_xor(s, m, 64);
  if (lane == 0) mod[wid] = s + ab[n];
}

// ---------------- LayerNorm + modulate -> x1 (bf16) ----------------
__global__ __launch_bounds__(256) void ln_mod_kernel(const float* __restrict__ x,
    const float* __restrict__ mod, short* __restrict__ x1, int b0) {
  int row = blockIdx.x * 4 + (threadIdx.x >> 6);
  int lane = threadIdx.x & 63;
  int b = b0 + (row >> 12);
  const f32x4* xr = (const f32x4*)(x + (size_t)row * Hn);
  f32x4 v[4];
  float s = 0.f, ss = 0.f;
#pragma unroll
  for (int i = 0; i < 4; ++i) {
    v[i] = xr[lane + 64 * i];
    s += v[i].x + v[i].y + v[i].z + v[i].w;
    ss += v[i].x * v[i].x + v[i].y * v[i].y + v[i].z * v[i].z + v[i].w * v[i].w;
  }
#pragma unroll
  for (int m = 1; m < 64; m <<= 1) {
    s += __shfl_xor(s, m, 64);
    ss += __shfl_xor(ss, m, 64);
  }
  float mu = s * (1.f / 1024.f);
  float var = ss * (1.f / 1024.f) - mu * mu;
  float r = rsqrtf(var + 1e-6f);
  const f32x4* shp = (const f32x4*)(mod + b * 3072);
  const f32x4* scp = (const f32x4*)(mod + b * 3072 + 1024);
#pragma unroll
  for (int i = 0; i < 4; ++i) {
    int k4 = lane + 64 * i;
    f32x4 sc = scp[k4], sh = shp[k4];
    short4v o;
    o.x = f2bf((v[i].x - mu) * r * (1.f + sc.x) + sh.x);
    o.y = f2bf((v[i].y - mu) * r * (1.f + sc.y) + sh.y);
    o.z = f2bf((v[i].z - mu) * r * (1.f + sc.z) + sh.z);
    o.w = f2bf((v[i].w - mu) * r * (1.f + sc.w) + sh.w);
    *(short4v*)&x1[(size_t)row * Hn + k4 * 4] = o;
  }
}

// ---------------- generic bf16 MFMA GEMM: out = A[M,K] @ W[N,K]^T (+epilogue) ----------------
// register-staged + padded LDS, 2-phase double-buffered; used for edge shapes.
#define SA_STR 40
template <int EPI>
__global__ __launch_bounds__(256) void gemm_k(
    const short* __restrict__ A, const short* __restrict__ W,
    const float* __restrict__ bias, const short* mul,
    const float* __restrict__ xres, const float* __restrict__ modp,
    void* outp, int N, int K, int b0) {
  __shared__ short sA[2][128 * SA_STR];
  __shared__ short sB[2][128 * SA_STR];
  int tid = threadIdx.x;
  int wave = tid >> 6, lane = tid & 63;
  int bm0 = blockIdx.y * 128;
  int bn0 = blockIdx.x * 128;
  int wm = (wave >> 1) * 64, wn = (wave & 1) * 64;
  int lrow = lane & 15, kh = (lane >> 4) * 8;
  int srow = tid >> 2;
  int scol = (tid & 3) * 8;

  f32x4 acc[4][4];
#pragma unroll
  for (int i = 0; i < 4; i++)
#pragma unroll
    for (int j = 0; j < 4; j++) acc[i][j] = (f32x4)0.f;

  // prologue: stage k0=0 into buffer 0
#pragma unroll
  for (int p = 0; p < 2; ++p) {
    int r = srow + p * 64;
    short8 av = *(const short8*)&A[(size_t)(bm0 + r) * K + scol];
    *(short8*)&sA[0][r * SA_STR + scol] = av;
    int n = bn0 + r;
    short8 bv = (short8)0;
    if (n < N) bv = *(const short8*)&W[(size_t)n * K + scol];
    *(short8*)&sB[0][r * SA_STR + scol] = bv;
  }
  __syncthreads();

  int cur = 0;
  for (int k0 = 0; k0 < K; k0 += 32) {
    bool have = (k0 + 32) < K;
    // issue next-tile global loads EARLY (latency hides under ds_read+MFMA)
    short8 av[2], bv[2];
    if (have) {
#pragma unroll
      for (int p = 0; p < 2; ++p) {
        int r = srow + p * 64;
        av[p] = *(const short8*)&A[(size_t)(bm0 + r) * K + k0 + 32 + scol];
        int n = bn0 + r;
        bv[p] = (short8)0;
        if (n < N) bv[p] = *(const short8*)&W[(size_t)n * K + k0 + 32 + scol];
      }
    }
    short8 af[4], bfr[4];
#pragma unroll
    for (int i = 0; i < 4; i++) af[i] = *(const short8*)&sA[cur][(wm + i * 16 + lrow) * SA_STR + kh];
#pragma unroll
    for (int j = 0; j < 4; j++) bfr[j] = *(const short8*)&sB[cur][(wn + j * 16 + lrow) * SA_STR + kh];
#pragma unroll
    for (int i = 0; i < 4; i++)
#pragma unroll
      for (int j = 0; j < 4; j++)
        acc[i][j] = __builtin_amdgcn_mfma_f32_16x16x32_bf16(af[i], bfr[j], acc[i][j], 0, 0, 0);
    // write staged regs into the other buffer (vmcnt wait lands here, after MFMA)
    if (have) {
      int nxt = cur ^ 1;
#pragma unroll
      for (int p = 0; p < 2; ++p) {
        int r = srow + p * 64;
        *(short8*)&sA[nxt][r * SA_STR + scol] = av[p];
        *(short8*)&sB[nxt][r * SA_STR + scol] = bv[p];
      }
    }
    __syncthreads();
    cur ^= 1;
  }

  int orow4 = (lane >> 4) * 4;
  int ocol = lane & 15;
#pragma unroll
  for (int i = 0; i < 4; i++)
#pragma unroll
    for (int j = 0; j < 4; j++)
#pragma unroll
      for (int r = 0; r < 4; r++) {
        int row = bm0 + wm + i * 16 + orow4 + r;
        int col = bn0 + wn + j * 16 + ocol;
        if (col >= N) continue;
        float v = acc[i][j][r];
        size_t idx = (size_t)row * N + col;
        if (EPI == 0) {
          ((short*)outp)[idx] = f2bf(v);
        } else if (EPI == 1) {
          ((short*)outp)[idx] = f2bf(v + bias[col]);
        } else if (EPI == 2) {
          ((short*)outp)[idx] = f2bf(silu_f(v + bias[col]));
        } else if (EPI == 3) {
          ((short*)outp)[idx] = f2bf(softplus_f(v + bias[col]));
        } else if (EPI == 4) {
          float t = silu_f(v + bias[col]) * bf2f(mul[idx]);
          ((short*)outp)[idx] = f2bf(t);
        } else if (EPI == 5) {
          ((float*)outp)[idx] = v;
        } else if (EPI == 6) {
          int b = b0 + (row >> 12);
          float t = v + bias[col];
          ((float*)outp)[idx] = xres[idx] + modp[b * 3072 + 2048 + col] * t;
        } else if (EPI == 7) {
          float t = silu_f(v) * bf2f(mul[idx]);
          ((short*)outp)[idx] = f2bf(t);
        } else if (EPI == 8) {
          // xproj: write fp32 dbl AND bf16 dt-slice (cols 0..63) in one pass
          ((float*)outp)[idx] = v;
          if (col < 64) ((short*)mul)[(size_t)row * 64 + col] = f2bf(v);
        }
      }
}

// ================== 256x256 8-phase counted-vmcnt GEMM (m201 template port) ==================
// 512 threads = 8 waves (2M x 4N); per-wave C = 128x64. BK=64, 2 LDS K-tile buffers.
// LDS layout per buffer: A then B; per matrix: half(row>>7) x 16KB; per half: 16 subtiles
// [rg(8) x cg(2)] of 1KB = 16 rows x 32 shorts, st_16x32 XOR-swizzled (byte^=((r16>>3)&1)<<5).
// Staged via global_load_lds with inverse-swizzled per-lane GLOBAL source (LDS dest linear).
// vmcnt(4) only at phases 4 and 8 (2 half-tiles = 4 loads in flight), raw s_barrier pairs.
// Requires M%256==0, N%256==0, K%128==0, (gridDim.x*gridDim.y)%8==0.
template <int EPI>
__global__ __launch_bounds__(512, 1) void gemm256_8ph(
    const short* __restrict__ A, const short* __restrict__ W,
    const short* mul, void* outp, int N, int K) {
  __shared__ short sMem[65536];  // 128 KiB
  char* sRaw = (char*)sMem;
  int tid = threadIdx.x;
  int wave = tid >> 6, lane = tid & 63;
  // bijective XCD-chunked swizzle (nwg % 8 == 0 guaranteed by caller)
  int nwg = gridDim.x * gridDim.y;
  int orig = blockIdx.y * gridDim.x + blockIdx.x;
  int cpx = nwg >> 3;
  int wg = (orig & 7) * cpx + (orig >> 3);
  int bm0 = (wg / gridDim.x) * 256;
  int bn0 = (wg % gridDim.x) * 256;
  int lrow = lane & 15;
  // swizzled lane offset within a 1KB subtile (read side)
  int lnOff = lrow * 64 + (((lane >> 4) * 16) ^ ((lrow >> 3) << 5));
  int aBase = (wave >> 2) * 16384 + lnOff;                 // A half chosen by wave M-row
  int bBase = 32768 + ((wave & 3) >> 1) * 16384 + lnOff;   // B half chosen by wave N-col
  int bSub = (wave & 1) * 4;                               // B subtile row-group base

  // stage-side inverse swizzle: thread's 2 chunks -> logical (row, 16B-chunk)
  int rS[2], cS[2], lSlot[2];
#pragma unroll
  for (int p = 0; p < 2; ++p) {
    int s = p * 8 + wave;
    rS[p] = (s >> 1) * 16 + (lane >> 2);
    cS[p] = (s & 1) * 4 + ((lane & 3) ^ (((lane >> 5) & 1) << 1));
    lSlot[p] = s * 1024 + lane * 16;  // linear LDS byte slot (wave-uniform base + lane*16)
  }

  f32x4 acc[8][4];
#pragma unroll
  for (int m = 0; m < 8; m++)
#pragma unroll
    for (int n = 0; n < 4; n++) acc[m][n] = (f32x4)0.f;

  // stage one half-tile (128 rows x 64 shorts) of matrix (isB) for K-tile tt, half hh
  auto stage = [&](const short* Mb, int row0, int tt, int hh, int isB) {
    int rb = (tt & 1) * 65536 + isB * 32768 + hh * 16384;
#pragma unroll
    for (int p = 0; p < 2; ++p) {
      const short* src = Mb + (size_t)(row0 + hh * 128 + rS[p]) * K + tt * 64 + cS[p] * 8;
      gld16(src, (short*)(sRaw + rb + lSlot[p]));
    }
  };

  short8 af[4][2], bfL[2][2], bfH[2][2];
  auto loadA = [&](int mg, int bsel) {
#pragma unroll
    for (int m = 0; m < 4; ++m)
#pragma unroll
      for (int ks = 0; ks < 2; ++ks)
        af[m][ks] =
            *(const short8*)(sRaw + bsel * 65536 + aBase + ((mg * 4 + m) * 2 + ks) * 1024);
  };
  auto loadB = [&](short8(&bf)[2][2], int ng, int bsel) {
#pragma unroll
    for (int n = 0; n < 2; ++n)
#pragma unroll
      for (int ks = 0; ks < 2; ++ks)
        bf[n][ks] = *(const short8*)(sRaw + bsel * 65536 + bBase +
                                     ((bSub + ng * 2 + n) * 2 + ks) * 1024);
  };
  auto mmaQ = [&](short8(&bf)[2][2], int mg, int ng) {
    __builtin_amdgcn_s_setprio(1);
#pragma unroll
    for (int ks = 0; ks < 2; ++ks)
#pragma unroll
      for (int m = 0; m < 4; ++m)
#pragma unroll
        for (int n = 0; n < 2; ++n)
          acc[mg * 4 + m][ng * 2 + n] = __builtin_amdgcn_mfma_f32_16x16x32_bf16(
              af[m][ks], bf[n][ks], acc[mg * 4 + m][ng * 2 + n], 0, 0, 0);
    __builtin_amdgcn_s_setprio(0);
  };

  // ---- prologue: tile0 (A_lo,A_hi,B_lo,B_hi) + tile1 (B_lo,B_hi) ----
  stage(A, bm0, 0, 0, 0);
  stage(A, bm0, 0, 1, 0);
  stage(W, bn0, 0, 0, 1);
  stage(W, bn0, 0, 1, 1);
  stage(W, bn0, 1, 0, 1);
  stage(W, bn0, 1, 1, 1);
  asm volatile("s_waitcnt vmcnt(4)" ::: "memory");  // tile0 drained; tile1.B in flight
  PBAR();

  int NT = K >> 6;
  for (int t = 0; t < NT; t += 2) {
    int s2 = (t + 2) < NT, s3 = (t + 3) < NT;
    // ---- phase 1: tile t (buf0) Q(m0-3, n0-1) ----
    loadA(0, 0);
    loadB(bfL, 0, 0);
    stage(A, bm0, t + 1, 0, 0);  // t+1.A_lo -> buf1 (A of buf1 last read prev ph7)
    PBAR();
    mmaQ(bfL, 0, 0);
    PBAR();
    // ---- phase 2: Q(m0-3, n2-3) ----
    loadB(bfH, 1, 0);
    stage(A, bm0, t + 1, 1, 0);  // t+1.A_hi
    PBAR();
    mmaQ(bfH, 0, 1);
    PBAR();
    // ---- phase 3: Q(m4-7, n0-1) ----
    loadA(1, 0);
    if (s2) stage(W, bn0, t + 2, 0, 1);  // t+2.B_lo -> buf0 (B of buf0 last read ph2)
    PBAR();
    mmaQ(bfL, 1, 0);
    PBAR();
    // ---- phase 4: Q(m4-7, n2-3); ensure tile t+1 staged before ph5 ----
    if (s2) {
      stage(W, bn0, t + 2, 1, 1);  // t+2.B_hi
      asm volatile("s_waitcnt vmcnt(4)" ::: "memory");
    } else {
      asm volatile("s_waitcnt vmcnt(0)" ::: "memory");
    }
    PBAR();
    mmaQ(bfH, 1, 1);
    PBAR();
    // ---- phase 5: tile t+1 (buf1) Q(m0-3, n0-1) ----
    loadA(0, 1);
    loadB(bfL, 0, 1);
    if (s2) stage(A, bm0, t + 2, 0, 0);  // t+2.A_lo -> buf0 (A of buf0 last read ph3)
    PBAR();
    mmaQ(bfL, 0, 0);
    PBAR();
    // ---- phase 6: Q(m0-3, n2-3) ----
    loadB(bfH, 1, 1);
    if (s2) stage(A, bm0, t + 2, 1, 0);  // t+2.A_hi
    PBAR();
    mmaQ(bfH, 0, 1);
    PBAR();
    // ---- phase 7: Q(m4-7, n0-1) ----
    loadA(1, 1);
    if (s3) stage(W, bn0, t + 3, 0, 1);  // t+3.B_lo -> buf1 (B of buf1 last read ph6)
    PBAR();
    mmaQ(bfL, 1, 0);
    PBAR();
    // ---- phase 8: Q(m4-7, n2-3); ensure tile t+2 staged before next ph1 ----
    if (s3) stage(W, bn0, t + 3, 1, 1);  // t+3.B_hi
    if (s2) {
      if (s3)
        asm volatile("s_waitcnt vmcnt(4)" ::: "memory");
      else
        asm volatile("s_waitcnt vmcnt(0)" ::: "memory");
    }
    PBAR();
    mmaQ(bfH, 1, 1);
    PBAR();
  }

  int wm = (wave >> 2) * 128, wn = (wave & 3) * 64;
  int orow4 = (lane >> 4) * 4;
  int ocol = lane & 15;
#pragma unroll
  for (int m = 0; m < 8; m++)
#pragma unroll
    for (int n = 0; n < 4; n++)
#pragma unroll
      for (int r = 0; r < 4; r++) {
        int row = bm0 + wm + m * 16 + orow4 + r;
        int col = bn0 + wn + n * 16 + ocol;
        float v = acc[m][n][r];
        size_t idx = (size_t)row * N + col;
        if (EPI == 0) {
          ((short*)outp)[idx] = f2bf(v);
        } else if (EPI == 7) {
          float t = silu_f(v) * bf2f(mul[idx]);
          ((short*)outp)[idx] = f2bf(t);
        }
      }
}

// ---------------- causal depthwise conv (DC=4) + SiLU ----------------
__global__ __launch_bounds__(256) void conv_kernel(const short* __restrict__ xm,
    const float* __restrict__ cw, const float* __restrict__ cb, short* __restrict__ xc) {
  size_t idx = (size_t)blockIdx.x * 256 + threadIdx.x;
  int d = (int)(idx & (DIn - 1));
  size_t bt = idx >> 11;
  int t = (int)(bt & (Ln - 1));
  f32x4 w = *(const f32x4*)(cw + d * 4);
  float wj[4] = {w.x, w.y, w.z, w.w};
  float acc = cb[d];
#pragma unroll
  for (int j = 0; j < 4; ++j) {
    int tt = t - 3 + j;
    if (tt >= 0) acc += bf2f(xm[(bt - 3 + j) * DIn + d]) * wj[j];
  }
  xc[idx] = f2bf(silu_f(acc));
}

// ================= chunked parallel selective scan =================
__global__ __launch_bounds__(256) void scan_part1(const short* __restrict__ dt,
    const short* __restrict__ xc, const float* __restrict__ dbl,
    const float* __restrict__ A_log, float* __restrict__ hq, float* __restrict__ sd) {
  __shared__ float sB[CLn * 16];
  int tid = threadIdx.x;
  int g = blockIdx.x * 256 + tid;
  int d = g & (DIn - 1);
  int r = g >> 11;
  int c = r & (NCH - 1);
  int b = r >> 6;
  size_t rb = (size_t)b * Ln + (size_t)c * CLn;
  {
    int row = tid >> 2, q = tid & 3;
    *(f32x4*)&sB[row * 16 + q * 4] = *(const f32x4*)(dbl + (rb + row) * 96 + 64 + q * 4);
  }
  __syncthreads();
  float A[16], h[16];
#pragma unroll
  for (int s = 0; s < 16; ++s) {
    A[s] = -__expf(A_log[d * 16 + s]);
    h[s] = 0.f;
  }
  bool st = true;
#pragma unroll
  for (int s = 1; s < 16; ++s)
    st = st && (fabsf(A[s] - (float)(s + 1) * A[0]) <= 1e-4f * fabsf(A[s]));
  float A0 = A[0];
  float sum = 0.f;
  const short* dp = dt + rb * DIn + d;
  const short* xp = xc + rb * DIn + d;
  short dtn = *dp, xcn = *xp;
  if (st) {
    for (int t = 0; t < CLn; ++t) {
      float dtv = bf2f(dtn), xv = bf2f(xcn);
      int tn = (t + 1 < CLn) ? t + 1 : t;
      dtn = dp[(size_t)tn * DIn];
      xcn = xp[(size_t)tn * DIn];
      float u = dtv * xv;
      sum += dtv;
      const f32x4* bp = (const f32x4*)&sB[t * 16];
      f32x4 b0 = bp[0], b1 = bp[1], b2 = bp[2], b3 = bp[3];
      float bv[16] = {b0.x, b0.y, b0.z, b0.w, b1.x, b1.y, b1.z, b1.w,
                      b2.x, b2.y, b2.z, b2.w, b3.x, b3.y, b3.z, b3.w};
      float qe = __expf(dtv * A0);
      float pk = qe;
#pragma unroll
      for (int s = 0; s < 16; ++s) {
        h[s] = h[s] * pk + u * bv[s];
        pk *= qe;
      }
    }
  } else {
    for (int t = 0; t < CLn; ++t) {
      float dtv = bf2f(dtn), xv = bf2f(xcn);
      int tn = (t + 1 < CLn) ? t + 1 : t;
      dtn = dp[(size_t)tn * DIn];
      xcn = xp[(size_t)tn * DIn];
      float u = dtv * xv;
      sum += dtv;
      const f32x4* bp = (const f32x4*)&sB[t * 16];
      f32x4 b0 = bp[0], b1 = bp[1], b2 = bp[2], b3 = bp[3];
      float bv[16] = {b0.x, b0.y, b0.z, b0.w, b1.x, b1.y, b1.z, b1.w,
                      b2.x, b2.y, b2.z, b2.w, b3.x, b3.y, b3.z, b3.w};
#pragma unroll
      for (int s = 0; s < 16; ++s) h[s] = h[s] * __expf(dtv * A[s]) + u * bv[s];
    }
  }
  size_t bd = (size_t)b * DIn + d;
  f32x4* out = (f32x4*)(hq + (bd * NCH + c) * 16);
#pragma unroll
  for (int i = 0; i < 4; ++i) {
    f32x4 o; o.x = h[4 * i]; o.y = h[4 * i + 1]; o.z = h[4 * i + 2]; o.w = h[4 * i + 3];
    out[i] = o;
  }
  sd[bd * NCH + c] = sum;
}

__global__ __launch_bounds__(256) void scan_combine(const float* __restrict__ A_log,
    const float* __restrict__ sd, float* hq) {
  int g = blockIdx.x * 256 + threadIdx.x;
  int s = g & 15;
  size_t bd = (size_t)(g >> 4);
  int d = (int)(bd & (DIn - 1));
  float A = -__expf(A_log[d * 16 + s]);
  float H = 0.f;
  for (int c = 0; c < NCH; ++c) {
    size_t idx = (bd * NCH + c) * 16 + s;
    float he = hq[idx];
    float e = __expf(A * sd[bd * NCH + c]);
    hq[idx] = H;
    H = H * e + he;
  }
}

__global__ __launch_bounds__(256) void scan_part2(const short* dt,
    const short* __restrict__ xc, const float* __restrict__ dbl,
    const float* __restrict__ A_log, const float* __restrict__ Dv,
    const float* __restrict__ hq, short* y) {
  __shared__ float sBC[CLn * 32];
  int tid = threadIdx.x;
  int g = blockIdx.x * 256 + tid;
  int d = g & (DIn - 1);
  int r = g >> 11;
  int c = r & (NCH - 1);
  int b = r >> 6;
  size_t rb = (size_t)b * Ln + (size_t)c * CLn;
  {
    int row = tid >> 2, q = tid & 3;
    const float* src = dbl + (rb + row) * 96 + 64 + q * 8;
    *(f32x4*)&sBC[row * 32 + q * 8] = *(const f32x4*)src;
    *(f32x4*)&sBC[row * 32 + q * 8 + 4] = *(const f32x4*)(src + 4);
  }
  __syncthreads();
  size_t bd = (size_t)b * DIn + d;
  float A[16], h[16];
#pragma unroll
  for (int s = 0; s < 16; ++s) A[s] = -__expf(A_log[d * 16 + s]);
  const f32x4* hin = (const f32x4*)(hq + (bd * NCH + c) * 16);
#pragma unroll
  for (int i = 0; i < 4; ++i) {
    f32x4 qv = hin[i];
    h[4 * i] = qv.x; h[4 * i + 1] = qv.y; h[4 * i + 2] = qv.z; h[4 * i + 3] = qv.w;
  }
  bool st = true;
#pragma unroll
  for (int s = 1; s < 16; ++s)
    st = st && (fabsf(A[s] - (float)(s + 1) * A[0]) <= 1e-4f * fabsf(A[s]));
  float A0 = A[0];
  float Dd = Dv[d];
  const short* dp = dt + rb * DIn + d;
  const short* xp = xc + rb * DIn + d;
  short* yp = y + rb * DIn + d;
  short dtn = *dp, xcn = *xp;
  if (st) {
    for (int t = 0; t < CLn; ++t) {
      float dtv = bf2f(dtn), xv = bf2f(xcn);
      int tn = (t + 1 < CLn) ? t + 1 : t;
      dtn = dp[(size_t)tn * DIn];
      xcn = xp[(size_t)tn * DIn];
      float u = dtv * xv;
      const f32x4* pp = (const f32x4*)&sBC[t * 32];
      f32x4 v0 = pp[0], v1 = pp[1], v2 = pp[2], v3 = pp[3];
      f32x4 v4 = pp[4], v5 = pp[5], v6 = pp[6], v7 = pp[7];
      float bc[32] = {v0.x, v0.y, v0.z, v0.w, v1.x, v1.y, v1.z, v1.w,
                      v2.x, v2.y, v2.z, v2.w, v3.x, v3.y, v3.z, v3.w,
                      v4.x, v4.y, v4.z, v4.w, v5.x, v5.y, v5.z, v5.w,
                      v6.x, v6.y, v6.z, v6.w, v7.x, v7.y, v7.z, v7.w};
      float qe = __expf(dtv * A0);
      float pk = qe, acc = 0.f;
#pragma unroll
      for (int s = 0; s < 16; ++s) {
        h[s] = h[s] * pk + u * bc[s];
        acc += h[s] * bc[16 + s];
        pk *= qe;
      }
      yp[(size_t)t * DIn] = f2bf(acc + xv * Dd);
    }
  } else {
    for (int t = 0; t < CLn; ++t) {
      float dtv = bf2f(dtn), xv = bf2f(xcn);
      int tn = (t + 1 < CLn) ? t + 1 : t;
      dtn = dp[(size_t)tn * DIn];
      xcn = xp[(size_t)tn * DIn];
      float u = dtv * xv;
      const f32x4* pp = (const f32x4*)&sBC[t * 32];
      f32x4 v0 = pp[0], v1 = pp[1], v2 = pp[2], v3 = pp[3];
      f32x4 v4 = pp[4], v5 = pp[5], v6 = pp[6], v7 = pp[7];
      float bc[32] = {v0.x, v0.y, v0.z, v0.w, v1.x, v1.y, v1.z, v1.w,
                      v2.x, v2.y, v2.z, v2.w, v3.x, v3.y, v3.z, v3.w,
                      v4.x, v4.y, v4.z, v4.w, v5.x, v5.y, v5.z, v5.w,
                      v6.x, v6.y, v6.z, v6.w, v7.x, v7.y, v7.z, v7.w};
      float acc = 0.f;
#pragma unroll
      for (int s = 0; s < 16; ++s) {
        h[s] = h[s] * __expf(dtv * A[s]) + u * bc[s];
        acc += h[s] * bc[16 + s];
      }
      yp[(size_t)t * DIn] = f2bf(acc + xv * Dd);
    }
  }
}

extern "C" void kernel_launch(void* const* d_in, const int* in_sizes, int n_in,
                              void* d_out, int out_size, void* d_ws, size_t ws_size,
                              hipStream_t stream) {
  const float* x = (const float*)d_in[0];
  const float* c = (const float*)d_in[1];
  const float* adaln_w = (const float*)d_in[2];
  const float* adaln_b = (const float*)d_in[3];
  const float* hgd_w1 = (const float*)d_in[4];
  const float* hgd_b1 = (const float*)d_in[5];
  const float* hgd_w2 = (const float*)d_in[6];
  const float* hgd_b2 = (const float*)d_in[7];
  const float* hgf_wm = (const float*)d_in[8];
  const float* hgf_bm = (const float*)d_in[9];
  const float* hgf_wr = (const float*)d_in[10];
  const float* hgf_br = (const float*)d_in[11];
  const float* hgf_wf = (const float*)d_in[12];
  const float* hgf_bf = (const float*)d_in[13];
  const float* in_w = (const float*)d_in[14];
  const float* conv_w = (const float*)d_in[15];
  const float* conv_b = (const float*)d_in[16];
  const float* xproj_w = (const float*)d_in[17];
  const float* dtproj_w = (const float*)d_in[18];
  const float* dt_bias = (const float*)d_in[19];
  const float* A_log = (const float*)d_in[20];
  const float* Dv = (const float*)d_in[21];
  const float* out_w = (const float*)d_in[22];
  (void)in_sizes; (void)n_in; (void)out_size;

  // ---- persistent region: bf16 weights + modulation ----
  char* ws = (char*)d_ws;
  size_t off = 0;
  auto alloc = [&](size_t bytes) -> void* {
    void* p = ws + off;
    off += (bytes + 255) & ~(size_t)255;
    return p;
  };
  short* w1b = (short*)alloc((size_t)256 * 1024 * 2);
  short* w2b = (short*)alloc((size_t)1024 * 256 * 2);
  short* wmb = (short*)alloc((size_t)256 * 1024 * 2);
  short* wrb = (short*)alloc((size_t)256 * 1024 * 2);
  short* wfb = (short*)alloc((size_t)1024 * 256 * 2);
  short* inwb = (short*)alloc((size_t)4096 * 1024 * 2);
  short* xpb = (short*)alloc((size_t)96 * 2048 * 2);
  short* dtpb = (short*)alloc((size_t)2048 * 64 * 2);
  short* owb = (short*)alloc((size_t)1024 * 2048 * 2);
  float* modb = (float*)alloc((size_t)Bn * 3072 * 4);
  size_t persist = off;

  // ---- batch-chunking: per-chunk bytes = Mc*14976 (incl. hq/sd) ----
  int BC = 8;
  while (BC > 1 && persist + (size_t)BC * Ln * 14976 > ws_size) BC >>= 1;
  int nchunk = 8 / BC;
  size_t Mc = (size_t)BC * Ln;

  short* x1 = (short*)alloc(Mc * 1024 * 2);
  short* hd = (short*)alloc(Mc * 1024 * 2);
  short* xm = (short*)alloc(Mc * 2048 * 2);   // in_proj x -> dt -> y_raw -> y
  short* xct = (short*)alloc(Mc * 2048 * 2);  // conv out; t1 aliases
  float* dbl = (float*)alloc(Mc * 96 * 4);
  short* dtb = (short*)alloc(Mc * 64 * 2);
  float* hq = (float*)alloc((size_t)BC * DIn * NCH * 16 * 4);
  float* sd = (float*)alloc((size_t)BC * DIn * NCH * 4);
  short* t1 = xct;

  auto conv1 = [&](const float* src, short* dst, int n) {
    f2bf4_kernel<<<(n / 4 + 255) / 256, 256, 0, stream>>>(src, dst, n / 4);
  };
  conv1(hgd_w1, w1b, 256 * 1024);
  conv1(hgd_w2, w2b, 1024 * 256);
  conv1(hgf_wm, wmb, 256 * 1024);
  conv1(hgf_wr, wrb, 256 * 1024);
  conv1(hgf_wf, wfb, 1024 * 256);
  conv1(in_w, inwb, 4096 * 1024);
  conv1(xproj_w, xpb, 96 * 2048);
  conv1(dtproj_w, dtpb, 2048 * 64);
  conv1(out_w, owb, 1024 * 2048);

  modcalc_kernel<<<(Bn * 3072) / 4, 256, 0, stream>>>(c, adaln_w, adaln_b, modb);

  dim3 blk(256);
  dim3 blk512(512);
  int gy = (int)(Mc / 128);
  int gy256 = (int)(Mc / 256);
  for (int ck = 0; ck < nchunk; ++ck) {
    int b0 = ck * BC;
    const float* xch = x + (size_t)b0 * Ln * Hn;
    float* och = (float*)d_out + (size_t)b0 * Ln * Hn;

    ln_mod_kernel<<<(int)(Mc / 4), blk, 0, stream>>>(xch, modb, x1, b0);
    gemm_k<2><<<dim3(2, gy), blk, 0, stream>>>(x1, w1b, hgd_b1, nullptr, nullptr, nullptr, t1, 256, 1024, 0);
    gemm_k<1><<<dim3(8, gy), blk, 0, stream>>>(t1, w2b, hgd_b2, nullptr, nullptr, nullptr, hd, 1024, 256, 0);
    gemm256_8ph<0><<<dim3(8, gy256), blk512, 0, stream>>>(hd, inwb, nullptr, xm, 2048, 1024);
    conv_kernel<<<(int)(Mc * 2048 / 256), blk, 0, stream>>>(xm, conv_w, conv_b, xct);
    // xproj: writes dbl (fp32) and dt-slice (bf16) in one pass (EPI=8)
    gemm_k<8><<<dim3(1, gy), blk, 0, stream>>>(xct, xpb, nullptr, dtb, nullptr, nullptr, dbl, 96, 2048, 0);
    gemm_k<3><<<dim3(16, gy), blk, 0, stream>>>(dtb, dtpb, dt_bias, nullptr, nullptr, nullptr, xm, 2048, 64, 0);
    // chunked parallel scan: dt(xm), xc(xct), B/C(dbl) -> y_raw in place in xm
    scan_part1<<<(int)(BC * 512), blk, 0, stream>>>(xm, xct, dbl, A_log, hq, sd);
    scan_combine<<<(int)(BC * 128), blk, 0, stream>>>(A_log, sd, hq);
    scan_part2<<<(int)(BC * 512), blk, 0, stream>>>(xm, xct, dbl, A_log, Dv, hq, xm);
    // gating: y = silu(hd @ Wz^T) * y_raw (in place)
    gemm256_8ph<7><<<dim3(8, gy256), blk512, 0, stream>>>(hd, inwb + (size_t)2048 * 1024, xm, xm, 2048, 1024);
    gemm256_8ph<0><<<dim3(4, gy256), blk512, 0, stream>>>(xm, owb, nullptr, hd, 1024, 2048);
    gemm_k<2><<<dim3(2, gy), blk, 0, stream>>>(hd, wmb, hgf_bm, nullptr, nullptr, nullptr, t1, 256, 1024, 0);
    gemm_k<4><<<dim3(2, gy), blk, 0, stream>>>(x1, wrb, hgf_br, t1, nullptr, nullptr, t1, 256, 1024, 0);
    gemm_k<6><<<dim3(8, gy), blk, 0, stream>>>(t1, wfb, hgf_bf, nullptr, xch, modb, och, 1024, 256, b0);
  }
}

// Round 5
// 1746.369 us; speedup vs baseline: 1.2038x; 1.2038x over previous
//
#include <hip/hip_runtime.h>

#define Hn 1024
#define Bn 8
#define Ln 4096
#define DIn 2048
#define NCH 64
#define CLn 64   // Ln / NCH

typedef __attribute__((ext_vector_type(8))) short short8;
typedef __attribute__((ext_vector_type(4))) short short4v;
typedef __attribute__((ext_vector_type(4))) float f32x4;

__device__ __forceinline__ float bf2f(short s) {
  return __uint_as_float(((unsigned)(unsigned short)s) << 16);
}
__device__ __forceinline__ short f2bf(float f) {
  unsigned u = __float_as_uint(f);
  u += 0x7fffu + ((u >> 16) & 1u);
  return (short)(u >> 16);
}
__device__ __forceinline__ float silu_f(float x) { return x / (1.f + __expf(-x)); }
// fast softplus: max(x,0)+log(1+exp(-|x|)); hw v_exp/v_log, abs err <= ~6e-8 (vs 0.0156 tol)
__device__ __forceinline__ float softplus_f(float x) {
  return fmaxf(x, 0.f) + __logf(1.f + __expf(-fabsf(x)));
}

__device__ __forceinline__ void gld16(const short* g, short* l) {
  __builtin_amdgcn_global_load_lds((const __attribute__((address_space(1))) void*)g,
                                   (__attribute__((address_space(3))) void*)l, 16, 0, 0);
}

#define PFENCE() __builtin_amdgcn_sched_barrier(0)
#define PBAR()            \
  do {                    \
    PFENCE();             \
    __builtin_amdgcn_s_barrier(); \
    PFENCE();             \
  } while (0)

// ---------------- fp32 -> bf16 convert (x4 vectorized) ----------------
__global__ __launch_bounds__(256) void f2bf4_kernel(const float* __restrict__ in,
                                                    short* __restrict__ out, int n4) {
  int i = blockIdx.x * 256 + threadIdx.x;
  if (i < n4) {
    f32x4 v = ((const f32x4*)in)[i];
    short4v o;
    o.x = f2bf(v.x); o.y = f2bf(v.y); o.z = f2bf(v.z); o.w = f2bf(v.w);
    ((short4v*)out)[i] = o;
  }
}

// ---------------- adaLN modulation ----------------
__global__ __launch_bounds__(256) void modcalc_kernel(const float* __restrict__ c,
    const float* __restrict__ aw, const float* __restrict__ ab, float* __restrict__ mod) {
  int wid = blockIdx.x * 4 + (threadIdx.x >> 6);
  int lane = threadIdx.x & 63;
  int b = wid / 3072, n = wid - b * 3072;
  const f32x4* cr = (const f32x4*)(c + b * Hn);
  const f32x4* wr = (const f32x4*)(aw + (size_t)n * Hn);
  float s = 0.f;
#pragma unroll
  for (int i = 0; i < 4; ++i) {
    f32x4 cv = cr[lane + 64 * i];
    f32x4 wv = wr[lane + 64 * i];
    s += silu_f(cv.x) * wv.x + silu_f(cv.y) * wv.y + silu_f(cv.z) * wv.z + silu_f(cv.w) * wv.w;
  }
#pragma unroll
  for (int m = 1; m < 64; m <<= 1) s += __shfl_xor(s, m, 64);
  if (lane == 0) mod[wid] = s + ab[n];
}

// ---------------- LayerNorm + modulate -> x1 (bf16) ----------------
__global__ __launch_bounds__(256) void ln_mod_kernel(const float* __restrict__ x,
    const float* __restrict__ mod, short* __restrict__ x1, int b0) {
  int row = blockIdx.x * 4 + (threadIdx.x >> 6);
  int lane = threadIdx.x & 63;
  int b = b0 + (row >> 12);
  const f32x4* xr = (const f32x4*)(x + (size_t)row * Hn);
  f32x4 v[4];
  float s = 0.f, ss = 0.f;
#pragma unroll
  for (int i = 0; i < 4; ++i) {
    v[i] = xr[lane + 64 * i];
    s += v[i].x + v[i].y + v[i].z + v[i].w;
    ss += v[i].x * v[i].x + v[i].y * v[i].y + v[i].z * v[i].z + v[i].w * v[i].w;
  }
#pragma unroll
  for (int m = 1; m < 64; m <<= 1) {
    s += __shfl_xor(s, m, 64);
    ss += __shfl_xor(ss, m, 64);
  }
  float mu = s * (1.f / 1024.f);
  float var = ss * (1.f / 1024.f) - mu * mu;
  float r = rsqrtf(var + 1e-6f);
  const f32x4* shp = (const f32x4*)(mod + b * 3072);
  const f32x4* scp = (const f32x4*)(mod + b * 3072 + 1024);
#pragma unroll
  for (int i = 0; i < 4; ++i) {
    int k4 = lane + 64 * i;
    f32x4 sc = scp[k4], sh = shp[k4];
    short4v o;
    o.x = f2bf((v[i].x - mu) * r * (1.f + sc.x) + sh.x);
    o.y = f2bf((v[i].y - mu) * r * (1.f + sc.y) + sh.y);
    o.z = f2bf((v[i].z - mu) * r * (1.f + sc.z) + sh.z);
    o.w = f2bf((v[i].w - mu) * r * (1.f + sc.w) + sh.w);
    *(short4v*)&x1[(size_t)row * Hn + k4 * 4] = o;
  }
}

// ---------------- generic bf16 MFMA GEMM: out = A[M,K] @ W[N,K]^T (+epilogue) ----------------
// register-staged + padded LDS, 2-phase double-buffered; used for edge shapes.
#define SA_STR 40
template <int EPI>
__global__ __launch_bounds__(256) void gemm_k(
    const short* __restrict__ A, const short* __restrict__ W,
    const float* __restrict__ bias, const short* mul,
    const float* __restrict__ xres, const float* __restrict__ modp,
    void* outp, int N, int K, int b0) {
  __shared__ short sA[2][128 * SA_STR];
  __shared__ short sB[2][128 * SA_STR];
  int tid = threadIdx.x;
  int wave = tid >> 6, lane = tid & 63;
  int bm0 = blockIdx.y * 128;
  int bn0 = blockIdx.x * 128;
  int wm = (wave >> 1) * 64, wn = (wave & 1) * 64;
  int lrow = lane & 15, kh = (lane >> 4) * 8;
  int srow = tid >> 2;
  int scol = (tid & 3) * 8;

  f32x4 acc[4][4];
#pragma unroll
  for (int i = 0; i < 4; i++)
#pragma unroll
    for (int j = 0; j < 4; j++) acc[i][j] = (f32x4)0.f;

  // prologue: stage k0=0 into buffer 0
#pragma unroll
  for (int p = 0; p < 2; ++p) {
    int r = srow + p * 64;
    short8 av = *(const short8*)&A[(size_t)(bm0 + r) * K + scol];
    *(short8*)&sA[0][r * SA_STR + scol] = av;
    int n = bn0 + r;
    short8 bv = (short8)0;
    if (n < N) bv = *(const short8*)&W[(size_t)n * K + scol];
    *(short8*)&sB[0][r * SA_STR + scol] = bv;
  }
  __syncthreads();

  int cur = 0;
  for (int k0 = 0; k0 < K; k0 += 32) {
    bool have = (k0 + 32) < K;
    // issue next-tile global loads EARLY (latency hides under ds_read+MFMA)
    short8 av[2], bv[2];
    if (have) {
#pragma unroll
      for (int p = 0; p < 2; ++p) {
        int r = srow + p * 64;
        av[p] = *(const short8*)&A[(size_t)(bm0 + r) * K + k0 + 32 + scol];
        int n = bn0 + r;
        bv[p] = (short8)0;
        if (n < N) bv[p] = *(const short8*)&W[(size_t)n * K + k0 + 32 + scol];
      }
    }
    short8 af[4], bfr[4];
#pragma unroll
    for (int i = 0; i < 4; i++) af[i] = *(const short8*)&sA[cur][(wm + i * 16 + lrow) * SA_STR + kh];
#pragma unroll
    for (int j = 0; j < 4; j++) bfr[j] = *(const short8*)&sB[cur][(wn + j * 16 + lrow) * SA_STR + kh];
#pragma unroll
    for (int i = 0; i < 4; i++)
#pragma unroll
      for (int j = 0; j < 4; j++)
        acc[i][j] = __builtin_amdgcn_mfma_f32_16x16x32_bf16(af[i], bfr[j], acc[i][j], 0, 0, 0);
    // write staged regs into the other buffer (vmcnt wait lands here, after MFMA)
    if (have) {
      int nxt = cur ^ 1;
#pragma unroll
      for (int p = 0; p < 2; ++p) {
        int r = srow + p * 64;
        *(short8*)&sA[nxt][r * SA_STR + scol] = av[p];
        *(short8*)&sB[nxt][r * SA_STR + scol] = bv[p];
      }
    }
    __syncthreads();
    cur ^= 1;
  }

  int orow4 = (lane >> 4) * 4;
  int ocol = lane & 15;
#pragma unroll
  for (int i = 0; i < 4; i++)
#pragma unroll
    for (int j = 0; j < 4; j++)
#pragma unroll
      for (int r = 0; r < 4; r++) {
        int row = bm0 + wm + i * 16 + orow4 + r;
        int col = bn0 + wn + j * 16 + ocol;
        if (col >= N) continue;
        float v = acc[i][j][r];
        size_t idx = (size_t)row * N + col;
        if (EPI == 0) {
          ((short*)outp)[idx] = f2bf(v);
        } else if (EPI == 1) {
          ((short*)outp)[idx] = f2bf(v + bias[col]);
        } else if (EPI == 2) {
          ((short*)outp)[idx] = f2bf(silu_f(v + bias[col]));
        } else if (EPI == 3) {
          ((short*)outp)[idx] = f2bf(softplus_f(v + bias[col]));
        } else if (EPI == 4) {
          float t = silu_f(v + bias[col]) * bf2f(mul[idx]);
          ((short*)outp)[idx] = f2bf(t);
        } else if (EPI == 5) {
          ((float*)outp)[idx] = v;
        } else if (EPI == 6) {
          int b = b0 + (row >> 12);
          float t = v + bias[col];
          ((float*)outp)[idx] = xres[idx] + modp[b * 3072 + 2048 + col] * t;
        } else if (EPI == 7) {
          float t = silu_f(v) * bf2f(mul[idx]);
          ((short*)outp)[idx] = f2bf(t);
        } else if (EPI == 8) {
          // xproj: write fp32 dbl AND bf16 dt-slice (cols 0..63) in one pass
          ((float*)outp)[idx] = v;
          if (col < 64) ((short*)mul)[(size_t)row * 64 + col] = f2bf(v);
        }
      }
}

// ================== 256x256 8-phase counted-vmcnt GEMM (m201 template port) ==================
// 512 threads = 8 waves (2M x 4N); per-wave C = 128x64. BK=64, 2 LDS K-tile buffers.
// LDS layout per buffer: A then B; per matrix: half(row>>7) x 16KB; per half: 16 subtiles
// [rg(8) x cg(2)] of 1KB = 16 rows x 32 shorts, st_16x32 XOR-swizzled (byte^=((r16>>3)&1)<<5).
// Staged via global_load_lds with inverse-swizzled per-lane GLOBAL source (LDS dest linear).
// vmcnt(4) only at phases 4 and 8 (2 half-tiles = 4 loads in flight), raw s_barrier pairs.
// Requires M%256==0, N%256==0, K%128==0, (gridDim.x*gridDim.y)%8==0.
template <int EPI>
__global__ __launch_bounds__(512, 1) void gemm256_8ph(
    const short* __restrict__ A, const short* __restrict__ W,
    const short* mul, void* outp, int N, int K) {
  __shared__ short sMem[65536];  // 128 KiB
  char* sRaw = (char*)sMem;
  int tid = threadIdx.x;
  int wave = tid >> 6, lane = tid & 63;
  // bijective XCD-chunked swizzle (nwg % 8 == 0 guaranteed by caller)
  int nwg = gridDim.x * gridDim.y;
  int orig = blockIdx.y * gridDim.x + blockIdx.x;
  int cpx = nwg >> 3;
  int wg = (orig & 7) * cpx + (orig >> 3);
  int bm0 = (wg / gridDim.x) * 256;
  int bn0 = (wg % gridDim.x) * 256;
  int lrow = lane & 15;
  // swizzled lane offset within a 1KB subtile (read side)
  int lnOff = lrow * 64 + (((lane >> 4) * 16) ^ ((lrow >> 3) << 5));
  int aBase = (wave >> 2) * 16384 + lnOff;                 // A half chosen by wave M-row
  int bBase = 32768 + ((wave & 3) >> 1) * 16384 + lnOff;   // B half chosen by wave N-col
  int bSub = (wave & 1) * 4;                               // B subtile row-group base

  // stage-side inverse swizzle: thread's 2 chunks -> logical (row, 16B-chunk)
  int rS[2], cS[2], lSlot[2];
#pragma unroll
  for (int p = 0; p < 2; ++p) {
    int s = p * 8 + wave;
    rS[p] = (s >> 1) * 16 + (lane >> 2);
    cS[p] = (s & 1) * 4 + ((lane & 3) ^ (((lane >> 5) & 1) << 1));
    lSlot[p] = s * 1024 + lane * 16;  // linear LDS byte slot (wave-uniform base + lane*16)
  }

  f32x4 acc[8][4];
#pragma unroll
  for (int m = 0; m < 8; m++)
#pragma unroll
    for (int n = 0; n < 4; n++) acc[m][n] = (f32x4)0.f;

  // stage one half-tile (128 rows x 64 shorts) of matrix (isB) for K-tile tt, half hh
  auto stage = [&](const short* Mb, int row0, int tt, int hh, int isB) {
    int rb = (tt & 1) * 65536 + isB * 32768 + hh * 16384;
#pragma unroll
    for (int p = 0; p < 2; ++p) {
      const short* src = Mb + (size_t)(row0 + hh * 128 + rS[p]) * K + tt * 64 + cS[p] * 8;
      gld16(src, (short*)(sRaw + rb + lSlot[p]));
    }
  };

  short8 af[4][2], bfL[2][2], bfH[2][2];
  auto loadA = [&](int mg, int bsel) {
#pragma unroll
    for (int m = 0; m < 4; ++m)
#pragma unroll
      for (int ks = 0; ks < 2; ++ks)
        af[m][ks] =
            *(const short8*)(sRaw + bsel * 65536 + aBase + ((mg * 4 + m) * 2 + ks) * 1024);
  };
  auto loadB = [&](short8(&bf)[2][2], int ng, int bsel) {
#pragma unroll
    for (int n = 0; n < 2; ++n)
#pragma unroll
      for (int ks = 0; ks < 2; ++ks)
        bf[n][ks] = *(const short8*)(sRaw + bsel * 65536 + bBase +
                                     ((bSub + ng * 2 + n) * 2 + ks) * 1024);
  };
  auto mmaQ = [&](short8(&bf)[2][2], int mg, int ng) {
    __builtin_amdgcn_s_setprio(1);
#pragma unroll
    for (int ks = 0; ks < 2; ++ks)
#pragma unroll
      for (int m = 0; m < 4; ++m)
#pragma unroll
        for (int n = 0; n < 2; ++n)
          acc[mg * 4 + m][ng * 2 + n] = __builtin_amdgcn_mfma_f32_16x16x32_bf16(
              af[m][ks], bf[n][ks], acc[mg * 4 + m][ng * 2 + n], 0, 0, 0);
    __builtin_amdgcn_s_setprio(0);
  };

  // ---- prologue: tile0 (A_lo,A_hi,B_lo,B_hi) + tile1 (B_lo,B_hi) ----
  stage(A, bm0, 0, 0, 0);
  stage(A, bm0, 0, 1, 0);
  stage(W, bn0, 0, 0, 1);
  stage(W, bn0, 0, 1, 1);
  stage(W, bn0, 1, 0, 1);
  stage(W, bn0, 1, 1, 1);
  asm volatile("s_waitcnt vmcnt(4)" ::: "memory");  // tile0 drained; tile1.B in flight
  PBAR();

  int NT = K >> 6;
  for (int t = 0; t < NT; t += 2) {
    int s2 = (t + 2) < NT, s3 = (t + 3) < NT;
    // ---- phase 1: tile t (buf0) Q(m0-3, n0-1) ----
    loadA(0, 0);
    loadB(bfL, 0, 0);
    stage(A, bm0, t + 1, 0, 0);  // t+1.A_lo -> buf1 (A of buf1 last read prev ph7)
    PBAR();
    mmaQ(bfL, 0, 0);
    PBAR();
    // ---- phase 2: Q(m0-3, n2-3) ----
    loadB(bfH, 1, 0);
    stage(A, bm0, t + 1, 1, 0);  // t+1.A_hi
    PBAR();
    mmaQ(bfH, 0, 1);
    PBAR();
    // ---- phase 3: Q(m4-7, n0-1) ----
    loadA(1, 0);
    if (s2) stage(W, bn0, t + 2, 0, 1);  // t+2.B_lo -> buf0 (B of buf0 last read ph2)
    PBAR();
    mmaQ(bfL, 1, 0);
    PBAR();
    // ---- phase 4: Q(m4-7, n2-3); ensure tile t+1 staged before ph5 ----
    if (s2) {
      stage(W, bn0, t + 2, 1, 1);  // t+2.B_hi
      asm volatile("s_waitcnt vmcnt(4)" ::: "memory");
    } else {
      asm volatile("s_waitcnt vmcnt(0)" ::: "memory");
    }
    PBAR();
    mmaQ(bfH, 1, 1);
    PBAR();
    // ---- phase 5: tile t+1 (buf1) Q(m0-3, n0-1) ----
    loadA(0, 1);
    loadB(bfL, 0, 1);
    if (s2) stage(A, bm0, t + 2, 0, 0);  // t+2.A_lo -> buf0 (A of buf0 last read ph3)
    PBAR();
    mmaQ(bfL, 0, 0);
    PBAR();
    // ---- phase 6: Q(m0-3, n2-3) ----
    loadB(bfH, 1, 1);
    if (s2) stage(A, bm0, t + 2, 1, 0);  // t+2.A_hi
    PBAR();
    mmaQ(bfH, 0, 1);
    PBAR();
    // ---- phase 7: Q(m4-7, n0-1) ----
    loadA(1, 1);
    if (s3) stage(W, bn0, t + 3, 0, 1);  // t+3.B_lo -> buf1 (B of buf1 last read ph6)
    PBAR();
    mmaQ(bfL, 1, 0);
    PBAR();
    // ---- phase 8: Q(m4-7, n2-3); ensure tile t+2 staged before next ph1 ----
    if (s3) stage(W, bn0, t + 3, 1, 1);  // t+3.B_hi
    if (s2) {
      if (s3)
        asm volatile("s_waitcnt vmcnt(4)" ::: "memory");
      else
        asm volatile("s_waitcnt vmcnt(0)" ::: "memory");
    }
    PBAR();
    mmaQ(bfH, 1, 1);
    PBAR();
  }

  int wm = (wave >> 2) * 128, wn = (wave & 3) * 64;
  int orow4 = (lane >> 4) * 4;
  int ocol = lane & 15;
#pragma unroll
  for (int m = 0; m < 8; m++)
#pragma unroll
    for (int n = 0; n < 4; n++)
#pragma unroll
      for (int r = 0; r < 4; r++) {
        int row = bm0 + wm + m * 16 + orow4 + r;
        int col = bn0 + wn + n * 16 + ocol;
        float v = acc[m][n][r];
        size_t idx = (size_t)row * N + col;
        if (EPI == 0) {
          ((short*)outp)[idx] = f2bf(v);
        } else if (EPI == 7) {
          float t = silu_f(v) * bf2f(mul[idx]);
          ((short*)outp)[idx] = f2bf(t);
        }
      }
}

// ---------------- causal depthwise conv (DC=4) + SiLU, x8 vectorized ----------------
// thread -> (bt, d0=8d block): short8 loads from 4 rows + short8 store
__global__ __launch_bounds__(256) void conv_kernel(const short* __restrict__ xm,
    const float* __restrict__ cw, const float* __restrict__ cb, short* __restrict__ xc) {
  size_t idx = (size_t)blockIdx.x * 256 + threadIdx.x;  // over (bt, d8)
  int d8 = (int)(idx & 255);
  size_t bt = idx >> 8;
  int t = (int)(bt & (Ln - 1));
  int d0 = d8 * 8;
  f32x4 w[8];
#pragma unroll
  for (int e = 0; e < 8; ++e) w[e] = ((const f32x4*)cw)[d0 + e];
  float acc[8];
  {
    const f32x4* cbp = (const f32x4*)(cb + d0);
    f32x4 c0 = cbp[0], c1 = cbp[1];
    acc[0] = c0.x; acc[1] = c0.y; acc[2] = c0.z; acc[3] = c0.w;
    acc[4] = c1.x; acc[5] = c1.y; acc[6] = c1.z; acc[7] = c1.w;
  }
#pragma unroll
  for (int j = 0; j < 4; ++j) {
    int tt = t - 3 + j;
    if (tt >= 0) {
      short8 v = *(const short8*)&xm[(bt - 3 + j) * DIn + d0];
#pragma unroll
      for (int e = 0; e < 8; ++e) acc[e] += bf2f(v[e]) * w[e][j];
    }
  }
  short8 o;
#pragma unroll
  for (int e = 0; e < 8; ++e) o[e] = f2bf(silu_f(acc[e]));
  *(short8*)&xc[bt * DIn + d0] = o;
}

// ================= chunked parallel selective scan =================
__global__ __launch_bounds__(256) void scan_part1(const short* __restrict__ dt,
    const short* __restrict__ xc, const float* __restrict__ dbl,
    const float* __restrict__ A_log, float* __restrict__ hq, float* __restrict__ sd) {
  __shared__ float sB[CLn * 16];
  int tid = threadIdx.x;
  int g = blockIdx.x * 256 + tid;
  int d = g & (DIn - 1);
  int r = g >> 11;
  int c = r & (NCH - 1);
  int b = r >> 6;
  size_t rb = (size_t)b * Ln + (size_t)c * CLn;
  {
    int row = tid >> 2, q = tid & 3;
    *(f32x4*)&sB[row * 16 + q * 4] = *(const f32x4*)(dbl + (rb + row) * 96 + 64 + q * 4);
  }
  __syncthreads();
  float A[16], h[16];
#pragma unroll
  for (int s = 0; s < 16; ++s) {
    A[s] = -__expf(A_log[d * 16 + s]);
    h[s] = 0.f;
  }
  bool st = true;
#pragma unroll
  for (int s = 1; s < 16; ++s)
    st = st && (fabsf(A[s] - (float)(s + 1) * A[0]) <= 1e-4f * fabsf(A[s]));
  float A0 = A[0];
  float sum = 0.f;
  const short* dp = dt + rb * DIn + d;
  const short* xp = xc + rb * DIn + d;
  short dtn = *dp, xcn = *xp;
  if (st) {
    for (int t = 0; t < CLn; ++t) {
      float dtv = bf2f(dtn), xv = bf2f(xcn);
      int tn = (t + 1 < CLn) ? t + 1 : t;
      dtn = dp[(size_t)tn * DIn];
      xcn = xp[(size_t)tn * DIn];
      float u = dtv * xv;
      sum += dtv;
      const f32x4* bp = (const f32x4*)&sB[t * 16];
      f32x4 b0 = bp[0], b1 = bp[1], b2 = bp[2], b3 = bp[3];
      float bv[16] = {b0.x, b0.y, b0.z, b0.w, b1.x, b1.y, b1.z, b1.w,
                      b2.x, b2.y, b2.z, b2.w, b3.x, b3.y, b3.z, b3.w};
      float qe = __expf(dtv * A0);
      float pk = qe;
#pragma unroll
      for (int s = 0; s < 16; ++s) {
        h[s] = h[s] * pk + u * bv[s];
        pk *= qe;
      }
    }
  } else {
    for (int t = 0; t < CLn; ++t) {
      float dtv = bf2f(dtn), xv = bf2f(xcn);
      int tn = (t + 1 < CLn) ? t + 1 : t;
      dtn = dp[(size_t)tn * DIn];
      xcn = xp[(size_t)tn * DIn];
      float u = dtv * xv;
      sum += dtv;
      const f32x4* bp = (const f32x4*)&sB[t * 16];
      f32x4 b0 = bp[0], b1 = bp[1], b2 = bp[2], b3 = bp[3];
      float bv[16] = {b0.x, b0.y, b0.z, b0.w, b1.x, b1.y, b1.z, b1.w,
                      b2.x, b2.y, b2.z, b2.w, b3.x, b3.y, b3.z, b3.w};
#pragma unroll
      for (int s = 0; s < 16; ++s) h[s] = h[s] * __expf(dtv * A[s]) + u * bv[s];
    }
  }
  size_t bd = (size_t)b * DIn + d;
  f32x4* out = (f32x4*)(hq + (bd * NCH + c) * 16);
#pragma unroll
  for (int i = 0; i < 4; ++i) {
    f32x4 o; o.x = h[4 * i]; o.y = h[4 * i + 1]; o.z = h[4 * i + 2]; o.w = h[4 * i + 3];
    out[i] = o;
  }
  sd[bd * NCH + c] = sum;
}

__global__ __launch_bounds__(256) void scan_combine(const float* __restrict__ A_log,
    const float* __restrict__ sd, float* hq) {
  int g = blockIdx.x * 256 + threadIdx.x;
  int s = g & 15;
  size_t bd = (size_t)(g >> 4);
  int d = (int)(bd & (DIn - 1));
  float A = -__expf(A_log[d * 16 + s]);
  float H = 0.f;
  for (int c = 0; c < NCH; ++c) {
    size_t idx = (bd * NCH + c) * 16 + s;
    float he = hq[idx];
    float e = __expf(A * sd[bd * NCH + c]);
    hq[idx] = H;
    H = H * e + he;
  }
}

__global__ __launch_bounds__(256) void scan_part2(const short* dt,
    const short* __restrict__ xc, const float* __restrict__ dbl,
    const float* __restrict__ A_log, const float* __restrict__ Dv,
    const float* __restrict__ hq, short* y) {
  __shared__ float sBC[CLn * 32];
  int tid = threadIdx.x;
  int g = blockIdx.x * 256 + tid;
  int d = g & (DIn - 1);
  int r = g >> 11;
  int c = r & (NCH - 1);
  int b = r >> 6;
  size_t rb = (size_t)b * Ln + (size_t)c * CLn;
  {
    int row = tid >> 2, q = tid & 3;
    const float* src = dbl + (rb + row) * 96 + 64 + q * 8;
    *(f32x4*)&sBC[row * 32 + q * 8] = *(const f32x4*)src;
    *(f32x4*)&sBC[row * 32 + q * 8 + 4] = *(const f32x4*)(src + 4);
  }
  __syncthreads();
  size_t bd = (size_t)b * DIn + d;
  float A[16], h[16];
#pragma unroll
  for (int s = 0; s < 16; ++s) A[s] = -__expf(A_log[d * 16 + s]);
  const f32x4* hin = (const f32x4*)(hq + (bd * NCH + c) * 16);
#pragma unroll
  for (int i = 0; i < 4; ++i) {
    f32x4 qv = hin[i];
    h[4 * i] = qv.x; h[4 * i + 1] = qv.y; h[4 * i + 2] = qv.z; h[4 * i + 3] = qv.w;
  }
  bool st = true;
#pragma unroll
  for (int s = 1; s < 16; ++s)
    st = st && (fabsf(A[s] - (float)(s + 1) * A[0]) <= 1e-4f * fabsf(A[s]));
  float A0 = A[0];
  float Dd = Dv[d];
  const short* dp = dt + rb * DIn + d;
  const short* xp = xc + rb * DIn + d;
  short* yp = y + rb * DIn + d;
  short dtn = *dp, xcn = *xp;
  if (st) {
    for (int t = 0; t < CLn; ++t) {
      float dtv = bf2f(dtn), xv = bf2f(xcn);
      int tn = (t + 1 < CLn) ? t + 1 : t;
      dtn = dp[(size_t)tn * DIn];
      xcn = xp[(size_t)tn * DIn];
      float u = dtv * xv;
      const f32x4* pp = (const f32x4*)&sBC[t * 32];
      f32x4 v0 = pp[0], v1 = pp[1], v2 = pp[2], v3 = pp[3];
      f32x4 v4 = pp[4], v5 = pp[5], v6 = pp[6], v7 = pp[7];
      float bc[32] = {v0.x, v0.y, v0.z, v0.w, v1.x, v1.y, v1.z, v1.w,
                      v2.x, v2.y, v2.z, v2.w, v3.x, v3.y, v3.z, v3.w,
                      v4.x, v4.y, v4.z, v4.w, v5.x, v5.y, v5.z, v5.w,
                      v6.x, v6.y, v6.z, v6.w, v7.x, v7.y, v7.z, v7.w};
      float qe = __expf(dtv * A0);
      float pk = qe, acc = 0.f;
#pragma unroll
      for (int s = 0; s < 16; ++s) {
        h[s] = h[s] * pk + u * bc[s];
        acc += h[s] * bc[16 + s];
        pk *= qe;
      }
      yp[(size_t)t * DIn] = f2bf(acc + xv * Dd);
    }
  } else {
    for (int t = 0; t < CLn; ++t) {
      float dtv = bf2f(dtn), xv = bf2f(xcn);
      int tn = (t + 1 < CLn) ? t + 1 : t;
      dtn = dp[(size_t)tn * DIn];
      xcn = xp[(size_t)tn * DIn];
      float u = dtv * xv;
      const f32x4* pp = (const f32x4*)&sBC[t * 32];
      f32x4 v0 = pp[0], v1 = pp[1], v2 = pp[2], v3 = pp[3];
      f32x4 v4 = pp[4], v5 = pp[5], v6 = pp[6], v7 = pp[7];
      float bc[32] = {v0.x, v0.y, v0.z, v0.w, v1.x, v1.y, v1.z, v1.w,
                      v2.x, v2.y, v2.z, v2.w, v3.x, v3.y, v3.z, v3.w,
                      v4.x, v4.y, v4.z, v4.w, v5.x, v5.y, v5.z, v5.w,
                      v6.x, v6.y, v6.z, v6.w, v7.x, v7.y, v7.z, v7.w};
      float acc = 0.f;
#pragma unroll
      for (int s = 0; s < 16; ++s) {
        h[s] = h[s] * __expf(dtv * A[s]) + u * bc[s];
        acc += h[s] * bc[16 + s];
      }
      yp[(size_t)t * DIn] = f2bf(acc + xv * Dd);
    }
  }
}

extern "C" void kernel_launch(void* const* d_in, const int* in_sizes, int n_in,
                              void* d_out, int out_size, void* d_ws, size_t ws_size,
                              hipStream_t stream) {
  const float* x = (const float*)d_in[0];
  const float* c = (const float*)d_in[1];
  const float* adaln_w = (const float*)d_in[2];
  const float* adaln_b = (const float*)d_in[3];
  const float* hgd_w1 = (const float*)d_in[4];
  const float* hgd_b1 = (const float*)d_in[5];
  const float* hgd_w2 = (const float*)d_in[6];
  const float* hgd_b2 = (const float*)d_in[7];
  const float* hgf_wm = (const float*)d_in[8];
  const float* hgf_bm = (const float*)d_in[9];
  const float* hgf_wr = (const float*)d_in[10];
  const float* hgf_br = (const float*)d_in[11];
  const float* hgf_wf = (const float*)d_in[12];
  const float* hgf_bf = (const float*)d_in[13];
  const float* in_w = (const float*)d_in[14];
  const float* conv_w = (const float*)d_in[15];
  const float* conv_b = (const float*)d_in[16];
  const float* xproj_w = (const float*)d_in[17];
  const float* dtproj_w = (const float*)d_in[18];
  const float* dt_bias = (const float*)d_in[19];
  const float* A_log = (const float*)d_in[20];
  const float* Dv = (const float*)d_in[21];
  const float* out_w = (const float*)d_in[22];
  (void)in_sizes; (void)n_in; (void)out_size;

  // ---- persistent region: bf16 weights + modulation ----
  char* ws = (char*)d_ws;
  size_t off = 0;
  auto alloc = [&](size_t bytes) -> void* {
    void* p = ws + off;
    off += (bytes + 255) & ~(size_t)255;
    return p;
  };
  short* w1b = (short*)alloc((size_t)256 * 1024 * 2);
  short* w2b = (short*)alloc((size_t)1024 * 256 * 2);
  short* wmb = (short*)alloc((size_t)256 * 1024 * 2);
  short* wrb = (short*)alloc((size_t)256 * 1024 * 2);
  short* wfb = (short*)alloc((size_t)1024 * 256 * 2);
  short* inwb = (short*)alloc((size_t)4096 * 1024 * 2);
  short* xpb = (short*)alloc((size_t)96 * 2048 * 2);
  short* dtpb = (short*)alloc((size_t)2048 * 64 * 2);
  short* owb = (short*)alloc((size_t)1024 * 2048 * 2);
  float* modb = (float*)alloc((size_t)Bn * 3072 * 4);
  size_t persist = off;

  // ---- batch-chunking: per-chunk bytes = Mc*14976 (incl. hq/sd) ----
  int BC = 8;
  while (BC > 1 && persist + (size_t)BC * Ln * 14976 > ws_size) BC >>= 1;
  int nchunk = 8 / BC;
  size_t Mc = (size_t)BC * Ln;

  short* x1 = (short*)alloc(Mc * 1024 * 2);
  short* hd = (short*)alloc(Mc * 1024 * 2);
  short* xm = (short*)alloc(Mc * 2048 * 2);   // in_proj x -> dt -> y_raw -> y
  short* xct = (short*)alloc(Mc * 2048 * 2);  // conv out; t1 aliases
  float* dbl = (float*)alloc(Mc * 96 * 4);
  short* dtb = (short*)alloc(Mc * 64 * 2);
  float* hq = (float*)alloc((size_t)BC * DIn * NCH * 16 * 4);
  float* sd = (float*)alloc((size_t)BC * DIn * NCH * 4);
  short* t1 = xct;

  auto conv1 = [&](const float* src, short* dst, int n) {
    f2bf4_kernel<<<(n / 4 + 255) / 256, 256, 0, stream>>>(src, dst, n / 4);
  };
  conv1(hgd_w1, w1b, 256 * 1024);
  conv1(hgd_w2, w2b, 1024 * 256);
  conv1(hgf_wm, wmb, 256 * 1024);
  conv1(hgf_wr, wrb, 256 * 1024);
  conv1(hgf_wf, wfb, 1024 * 256);
  conv1(in_w, inwb, 4096 * 1024);
  conv1(xproj_w, xpb, 96 * 2048);
  conv1(dtproj_w, dtpb, 2048 * 64);
  conv1(out_w, owb, 1024 * 2048);

  modcalc_kernel<<<(Bn * 3072) / 4, 256, 0, stream>>>(c, adaln_w, adaln_b, modb);

  dim3 blk(256);
  dim3 blk512(512);
  int gy = (int)(Mc / 128);
  int gy256 = (int)(Mc / 256);
  for (int ck = 0; ck < nchunk; ++ck) {
    int b0 = ck * BC;
    const float* xch = x + (size_t)b0 * Ln * Hn;
    float* och = (float*)d_out + (size_t)b0 * Ln * Hn;

    ln_mod_kernel<<<(int)(Mc / 4), blk, 0, stream>>>(xch, modb, x1, b0);
    gemm_k<2><<<dim3(2, gy), blk, 0, stream>>>(x1, w1b, hgd_b1, nullptr, nullptr, nullptr, t1, 256, 1024, 0);
    gemm_k<1><<<dim3(8, gy), blk, 0, stream>>>(t1, w2b, hgd_b2, nullptr, nullptr, nullptr, hd, 1024, 256, 0);
    gemm256_8ph<0><<<dim3(8, gy256), blk512, 0, stream>>>(hd, inwb, nullptr, xm, 2048, 1024);
    conv_kernel<<<(int)Mc, blk, 0, stream>>>(xm, conv_w, conv_b, xct);
    // xproj: writes dbl (fp32) and dt-slice (bf16) in one pass (EPI=8)
    gemm_k<8><<<dim3(1, gy), blk, 0, stream>>>(xct, xpb, nullptr, dtb, nullptr, nullptr, dbl, 96, 2048, 0);
    gemm_k<3><<<dim3(16, gy), blk, 0, stream>>>(dtb, dtpb, dt_bias, nullptr, nullptr, nullptr, xm, 2048, 64, 0);
    // chunked parallel scan: dt(xm), xc(xct), B/C(dbl) -> y_raw in place in xm
    scan_part1<<<(int)(BC * 512), blk, 0, stream>>>(xm, xct, dbl, A_log, hq, sd);
    scan_combine<<<(int)(BC * 128), blk, 0, stream>>>(A_log, sd, hq);
    scan_part2<<<(int)(BC * 512), blk, 0, stream>>>(xm, xct, dbl, A_log, Dv, hq, xm);
    // gating: y = silu(hd @ Wz^T) * y_raw (in place)
    gemm256_8ph<7><<<dim3(8, gy256), blk512, 0, stream>>>(hd, inwb + (size_t)2048 * 1024, xm, xm, 2048, 1024);
    gemm256_8ph<0><<<dim3(4, gy256), blk512, 0, stream>>>(xm, owb, nullptr, hd, 1024, 2048);
    gemm_k<2><<<dim3(2, gy), blk, 0, stream>>>(hd, wmb, hgf_bm, nullptr, nullptr, nullptr, t1, 256, 1024, 0);
    gemm_k<4><<<dim3(2, gy), blk, 0, stream>>>(x1, wrb, hgf_br, t1, nullptr, nullptr, t1, 256, 1024, 0);
    gemm_k<6><<<dim3(8, gy), blk, 0, stream>>>(t1, wfb, hgf_bf, nullptr, xch, modb, och, 1024, 256, b0);
  }
}